// Round 9
// baseline (6997.028 us; speedup 1.0000x reference)
//
#include <hip/hip_runtime.h>
#include <hip/hip_bf16.h>

// Problem constants
#define BATCH   64
#define SEQ     512
#define IN0     512
#define HID     128
#define G3      384   // 3*HID
#define NLAY    5
#define CHUNK   8     // handoff granularity (one release/acquire per CHUNK steps)

typedef _Float16 f16x8 __attribute__((ext_vector_type(8)));
typedef float    f32x4 __attribute__((ext_vector_type(4)));

static __device__ __forceinline__ float sigf(float x) {
    return __builtin_amdgcn_rcpf(1.f + __expf(-x));
}
static __device__ __forceinline__ float tanh_fast(float x) {
    // exp(-2|x|) = exp2(|x| * -2*log2(e)); single mul + v_exp
    const float e = exp2f(fabsf(x) * -2.885390082f);
    return copysignf((1.f - e) * __builtin_amdgcn_rcpf(1.f + e), x);
}

// ---------------------------------------------------------------------------
// gemm_gx (MFMA): gx0[32768][384] = x[32768][512] @ w_ih0[384][512]^T + b_ih0
// (unchanged)
// ---------------------------------------------------------------------------
__global__ __launch_bounds__(256) void gemm_gx(const float* __restrict__ A,
                                               const float* __restrict__ W,
                                               const float* __restrict__ bias,
                                               float* __restrict__ gx)
{
    __shared__ __align__(16) _Float16 As[64][40];   // [m][k0..31], pad 40 (80B rows)
    __shared__ __align__(16) _Float16 Bs[64][40];   // [n][k0..31]

    const int tid  = threadIdx.x;
    const int lane = tid & 63;
    const int wv   = tid >> 6;          // m-subtile
    const int n16  = lane & 15;
    const int quad = lane >> 4;
    const int row0 = blockIdx.x * 64;
    const int col0 = blockIdx.y * 64;
    const int r    = tid >> 2;          // staging row 0..63
    const int kc   = (tid & 3) * 8;     // staging k offset 0,8,16,24

    f32x4 acc[4];
    #pragma unroll
    for (int nt = 0; nt < 4; nt++) acc[nt] = (f32x4){0.f, 0.f, 0.f, 0.f};

    for (int k0 = 0; k0 < IN0; k0 += 32) {
        // ---- stage A (x) tile, f32 -> f16 ----
        {
            const float* Ap = A + (size_t)(row0 + r) * IN0 + k0 + kc;
            float4 a0 = *(const float4*)(Ap);
            float4 a1 = *(const float4*)(Ap + 4);
            f16x8 v;
            v[0] = (_Float16)a0.x; v[1] = (_Float16)a0.y; v[2] = (_Float16)a0.z; v[3] = (_Float16)a0.w;
            v[4] = (_Float16)a1.x; v[5] = (_Float16)a1.y; v[6] = (_Float16)a1.z; v[7] = (_Float16)a1.w;
            *(f16x8*)&As[r][kc] = v;
        }
        // ---- stage B (w_ih0) tile ----
        {
            const float* Wp = W + (size_t)(col0 + r) * IN0 + k0 + kc;
            float4 b0 = *(const float4*)(Wp);
            float4 b1 = *(const float4*)(Wp + 4);
            f16x8 v;
            v[0] = (_Float16)b0.x; v[1] = (_Float16)b0.y; v[2] = (_Float16)b0.z; v[3] = (_Float16)b0.w;
            v[4] = (_Float16)b1.x; v[5] = (_Float16)b1.y; v[6] = (_Float16)b1.z; v[7] = (_Float16)b1.w;
            *(f16x8*)&Bs[r][kc] = v;
        }
        __syncthreads();

        const f16x8 af = *(const f16x8*)&As[wv * 16 + n16][quad * 8];
        #pragma unroll
        for (int nt = 0; nt < 4; nt++) {
            const f16x8 bfr = *(const f16x8*)&Bs[nt * 16 + n16][quad * 8];
            acc[nt] = __builtin_amdgcn_mfma_f32_16x16x32_f16(af, bfr, acc[nt], 0, 0, 0);
        }
        __syncthreads();
    }

    // epilogue: bias + store (lane owns rows quad*4+r4 of subtile, col n16)
    #pragma unroll
    for (int nt = 0; nt < 4; nt++) {
        const int col = col0 + nt * 16 + n16;
        const float bb = bias[col];
        #pragma unroll
        for (int r4 = 0; r4 < 4; r4++) {
            const int row = row0 + wv * 16 + quad * 4 + r4;
            gx[(size_t)row * G3 + col] = acc[nt][r4] + bb;
        }
    }
}

// ---------------------------------------------------------------------------
// gru_pipeline (R19): R17/R18 two-team structure, third (decisive) attempt
// at the register budget. __launch_bounds__(1024,{4,1}) both produced a
// 64-VGPR budget (8 waves/EU heuristic) -> B-frag spill -> 7ms. This time
// the backend attribute is pinned DIRECTLY:
//   amdgpu_flat_work_group_size(1024,1024) + amdgpu_waves_per_eu(4,4)
// -> allocator budget = maxVGPRs @ 4 waves/EU = 128, same envelope the
// 512-thread kernel fit (116). Teams: team = tid>>9 handles batch group
// g = (bid&1)*2 + team; private hS ring + flag barrier per team; teams
// couple only at the chunk-end __syncthreads.
// ---------------------------------------------------------------------------
__global__
__attribute__((amdgpu_flat_work_group_size(1024, 1024), amdgpu_waves_per_eu(4, 4)))
void gru_pipeline(
    const float* __restrict__ gx0,        // [64][512][384]
    const float* __restrict__ w_ih_rest,  // [4][384][128]
    const float* __restrict__ w_hh,       // [5][384][128]
    const float* __restrict__ b_ih,       // [5][384]
    const float* __restrict__ b_hh,       // [5][384]
    _Float16* __restrict__ hmid,          // [4][4][512][16][128]
    float* __restrict__ hlast,            // [64][128]
    int* __restrict__ flags)              // [16]
{
    const int l    = blockIdx.x >> 1;
    const int tid  = threadIdx.x;
    const int team = tid >> 9;            // 0 or 1
    const int ttid = tid & 511;           // team-local tid
    const int g    = ((blockIdx.x & 1) << 1) | team;
    const int bm0  = g * 16;
    const int lane = tid & 63;
    const int n16  = lane & 15;
    const int quad = lane >> 4;
    const int wv   = (tid >> 6) & 7;      // team-local wave 0..7
    const int j    = wv * 16 + n16;       // hidden index this lane finalizes

    __shared__ __align__(16) _Float16 hS[2][CHUNK][16][136];  // per-team h ring
    __shared__ int barcnt[2];

    // ---- B-frags for w_hh ----
    f16x8 bf[3][4];
    {
        const float* wb = w_hh + (size_t)l * G3 * HID;
        #pragma unroll
        for (int tau = 0; tau < 3; tau++)
            #pragma unroll
            for (int kc = 0; kc < 4; kc++) {
                const float* wp = wb + (size_t)(tau * 128 + j) * HID + kc * 32 + quad * 8;
                f16x8 v;
                #pragma unroll
                for (int i = 0; i < 8; i++) v[i] = (_Float16)wp[i];
                bf[tau][kc] = v;
            }
    }
    // ---- B-frags for w_ih (layers >= 1) ----
    f16x8 bi[3][4];
    if (l > 0) {
        const float* wb = w_ih_rest + (size_t)(l - 1) * G3 * HID;
        #pragma unroll
        for (int tau = 0; tau < 3; tau++)
            #pragma unroll
            for (int kc = 0; kc < 4; kc++) {
                const float* wp = wb + (size_t)(tau * 128 + j) * HID + kc * 32 + quad * 8;
                f16x8 v;
                #pragma unroll
                for (int i = 0; i < 8; i++) v[i] = (_Float16)wp[i];
                bi[tau][kc] = v;
            }
    }
    // gate biases (gx0 already contains b_ih for layer 0); folded into acc init
    const float bcr = b_hh[l * G3 + j]       + ((l > 0) ? b_ih[l * G3 + j]       : 0.f);
    const float bcz = b_hh[l * G3 + j + 128] + ((l > 0) ? b_ih[l * G3 + j + 128] : 0.f);
    const float bcn = b_hh[l * G3 + j + 256];                      // n-gate: b_hh inside r*(...)
    const float bxn = (l > 0) ? b_ih[l * G3 + j + 256] : 0.f;      // n-gate: b_ih outside

    // ---- zero own team's h ring ----
    for (int i = ttid; i < CHUNK * 16 * 136; i += 512)
        ((_Float16*)hS[team])[i] = (_Float16)0.f;
    float vhp[4] = {0.f, 0.f, 0.f, 0.f};
    if (ttid == 0) barcnt[team] = 0;

    // ---- layer-0 gx pointers + preload t=0 ----
    const float* pR[4];
    float xr[4], xz[4], xn[4];
    if (l == 0) {
        #pragma unroll
        for (int r = 0; r < 4; r++) {
            pR[r] = gx0 + (size_t)(bm0 + quad * 4 + r) * SEQ * G3 + j;
            xr[r] = pR[r][0]; xz[r] = pR[r][128]; xn[r] = pR[r][256];
            pR[r] += G3;
        }
    }

    const _Float16* hprev = (l > 0) ? hmid + (size_t)((l - 1) * 4 + g) * SEQ * 2048 : (const _Float16*)nullptr;
    _Float16*       hpub  = (l < 4) ? hmid + (size_t)(l * 4 + g) * SEQ * 2048 : (_Float16*)nullptr;
    int*       dstflag = (l < 4) ? &flags[l * 4 + g] : (int*)nullptr;
    const int* srcflag = (l > 0) ? &flags[(l - 1) * 4 + g] : (const int*)nullptr;

    f16x8 ap[4];                             // h_prev(t) A-frags
    const int hoff = n16 * 128 + quad * 8;   // A-frag base (m=n16, k=quad*8)

    __syncthreads();   // both teams' hS zero + barcnt visible

    volatile int* bc = &barcnt[team];
    int btarget = 0;

    for (int c = 0; c < SEQ / CHUNK; c++) {
        const int t0 = c * CHUNK;

        if (l > 0) {
            // once-per-chunk: relaxed spin, then ONE acquire load (buffer_inv)
            const int need = t0 + CHUNK;
            int v = __hip_atomic_load(srcflag, __ATOMIC_RELAXED, __HIP_MEMORY_SCOPE_AGENT);
            while (v < need) {
                __builtin_amdgcn_s_sleep(2);
                v = __hip_atomic_load(srcflag, __ATOMIC_RELAXED, __HIP_MEMORY_SCOPE_AGENT);
            }
            (void)__hip_atomic_load(srcflag, __ATOMIC_ACQUIRE, __HIP_MEMORY_SCOPE_AGENT);
            __asm__ volatile("" ::: "memory");
            const _Float16* hp = hprev + (size_t)t0 * 2048 + hoff;
            #pragma unroll
            for (int kc = 0; kc < 4; kc++) ap[kc] = *(const f16x8*)(hp + kc * 32);
        }

        #pragma unroll
        for (int i = 0; i < CHUNK; i++) {
            const int t = t0 + i;

            // ---- team-scoped LDS flag barrier: no vmcnt drain ----
            __asm__ volatile("" ::: "memory");
            if (lane == 0) atomicAdd(&barcnt[team], 1);
            btarget += 8;
            while (*bc < btarget) { __builtin_amdgcn_s_sleep(1); }
            __asm__ volatile("" ::: "memory");

            // issue af LDS reads first (latency overlapped by ih MFMAs below)
            const int rb = (i + CHUNK - 1) & (CHUNK - 1);   // h(t-1) slot
            f16x8 af[4];
            #pragma unroll
            for (int kc = 0; kc < 4; kc++)
                af[kc] = *(const f16x8*)&hS[team][rb][n16][kc * 32 + quad * 8];

            // ih MFMAs (register inputs, no LDS dependency) — issue first.
            // bias folding: ai2 starts at bxn (n-gate b_ih, outside r*()).
            f32x4 ai0 = {0.f, 0.f, 0.f, 0.f}, ai1 = ai0;
            f32x4 ai2 = {bxn, bxn, bxn, bxn};
            if (l > 0) {
                #pragma unroll
                for (int kc = 0; kc < 4; kc++) {
                    ai0 = __builtin_amdgcn_mfma_f32_16x16x32_f16(ap[kc], bi[0][kc], ai0, 0, 0, 0);
                    ai1 = __builtin_amdgcn_mfma_f32_16x16x32_f16(ap[kc], bi[1][kc], ai1, 0, 0, 0);
                    ai2 = __builtin_amdgcn_mfma_f32_16x16x32_f16(ap[kc], bi[2][kc], ai2, 0, 0, 0);
                }
            }

            // EARLY in-chunk prefetch of h_prev(t+1): ap dead after ih MFMAs;
            // hh MFMAs + finalize + barrier cover the latency.
            if (l > 0 && i < CHUNK - 1) {
                const _Float16* hp = hprev + (size_t)(t + 1) * 2048 + hoff;
                #pragma unroll
                for (int kc = 0; kc < 4; kc++) ap[kc] = *(const f16x8*)(hp + kc * 32);
            }

            // layer-0: issue gx(t+1) prefetch
            float nr[4], nz[4], nn[4];
            if (l == 0) {
                #pragma unroll
                for (int r = 0; r < 4; r++) {
                    nr[r] = pR[r][0]; nz[r] = pR[r][128]; nn[r] = pR[r][256];
                }
                if (t + 1 < SEQ) {
                    #pragma unroll
                    for (int r = 0; r < 4; r++) pR[r] += G3;
                }
            }

            // hh MFMAs — biases folded into C-init (bcr, bcz, bcn)
            f32x4 ah0 = {bcr, bcr, bcr, bcr};
            f32x4 ah1 = {bcz, bcz, bcz, bcz};
            f32x4 ah2 = {bcn, bcn, bcn, bcn};
            #pragma unroll
            for (int kc = 0; kc < 4; kc++) {
                ah0 = __builtin_amdgcn_mfma_f32_16x16x32_f16(af[kc], bf[0][kc], ah0, 0, 0, 0);
                ah1 = __builtin_amdgcn_mfma_f32_16x16x32_f16(af[kc], bf[1][kc], ah1, 0, 0, 0);
                ah2 = __builtin_amdgcn_mfma_f32_16x16x32_f16(af[kc], bf[2][kc], ah2, 0, 0, 0);
            }

            // finalize: lane owns (m = quad*4+r, j) for all gates
            #pragma unroll
            for (int r = 0; r < 4; r++) {
                const float sxr = (l == 0) ? xr[r] : ai0[r];
                const float sxz = (l == 0) ? xz[r] : ai1[r];
                const float sxn = (l == 0) ? xn[r] : ai2[r];
                const float rg  = sigf(sxr + ah0[r]);
                const float zg  = sigf(sxz + ah1[r]);
                const float th  = tanh_fast(fmaf(rg, ah2[r], sxn));
                const float hnew = fmaf(zg, vhp[r] - th, th);   // (1-z)n + z h
                vhp[r] = hnew;
                hS[team][i][quad * 4 + r][j] = (_Float16)hnew;  // single h write (ring)
                if (l == 4 && t == SEQ - 1)
                    hlast[(bm0 + quad * 4 + r) * 128 + j] = hnew;
            }

            if (l == 0) {
                #pragma unroll
                for (int r = 0; r < 4; r++) { xr[r] = nr[r]; xz[r] = nz[r]; xn[r] = nn[r]; }
            }
        }

        // ---- chunk boundary: flush own ring -> hmid (coalesced), RELEASE ----
        __syncthreads();                       // both teams' hS writes visible
        if (l < 4) {
            _Float16* dstc = hpub + (size_t)t0 * 2048;
            {
                const int seg0 = ttid;           // 0..511 (team-local)
                const int seg1 = ttid + 512;
                const int seg2 = ttid + 1024;
                const int seg3 = ttid + 1536;
                f16x8 v0 = *(const f16x8*)&hS[team][(seg0 >> 8)][(seg0 >> 4) & 15][(seg0 & 15) * 8];
                f16x8 v1 = *(const f16x8*)&hS[team][(seg1 >> 8)][(seg1 >> 4) & 15][(seg1 & 15) * 8];
                f16x8 v2 = *(const f16x8*)&hS[team][(seg2 >> 8)][(seg2 >> 4) & 15][(seg2 & 15) * 8];
                f16x8 v3 = *(const f16x8*)&hS[team][(seg3 >> 8)][(seg3 >> 4) & 15][(seg3 & 15) * 8];
                *(f16x8*)(dstc + (seg0 >> 4) * 128 + (seg0 & 15) * 8) = v0;
                *(f16x8*)(dstc + (seg1 >> 4) * 128 + (seg1 & 15) * 8) = v1;
                *(f16x8*)(dstc + (seg2 >> 4) * 128 + (seg2 & 15) * 8) = v2;
                *(f16x8*)(dstc + (seg3 >> 4) * 128 + (seg3 & 15) * 8) = v3;
            }
        }
        __syncthreads();                       // drains vmcnt (stores retired)
        if (l < 4 && ttid == 0)
            __hip_atomic_store(dstflag, t0 + CHUNK, __ATOMIC_RELEASE, __HIP_MEMORY_SCOPE_AGENT);
    }
}

// ---------------------------------------------------------------------------
// fc: out[b][o] = hlast[b][:] . fc_w[o][:] + fc_b[o]
// ---------------------------------------------------------------------------
__global__ __launch_bounds__(128) void fc_kernel(const float* __restrict__ hlast,
                                                 const float* __restrict__ fc_w,
                                                 const float* __restrict__ fc_b,
                                                 float* __restrict__ out)
{
    const int b = blockIdx.x;
    const int o = threadIdx.x;
    if (o < 96) {
        const float* h = hlast + (size_t)b * HID;
        const float* wrow = fc_w + o * HID;
        float acc = fc_b[o];
        #pragma unroll 4
        for (int k = 0; k < HID; k++) acc = fmaf(h[k], wrow[k], acc);
        out[b * 96 + o] = acc;
    }
}

// ---------------------------------------------------------------------------
extern "C" void kernel_launch(void* const* d_in, const int* in_sizes, int n_in,
                              void* d_out, int out_size, void* d_ws, size_t ws_size,
                              hipStream_t stream)
{
    const float* x         = (const float*)d_in[0]; // [64][512][512]
    const float* w_ih0     = (const float*)d_in[1]; // [384][512]
    const float* w_ih_rest = (const float*)d_in[2]; // [4][384][128]
    const float* w_hh      = (const float*)d_in[3]; // [5][384][128]
    const float* b_ih      = (const float*)d_in[4]; // [5][384]
    const float* b_hh      = (const float*)d_in[5]; // [5][384]
    const float* fc_w      = (const float*)d_in[6]; // [96][128]
    const float* fc_b      = (const float*)d_in[7]; // [96]
    float* out = (float*)d_out;                     // [64][96]

    // workspace layout:
    //   [0,256)              flags (16 ints, zeroed each launch)
    //   [256, +50331648)     gxbuf fp32 [64][512][384]
    //   [.., +33554432)      hmid  f16  [4][4][512][16][128]
    //   [.., +32768)         hlast fp32 [64][128]
    int*      flags = (int*)d_ws;
    float*    gxbuf = (float*)((char*)d_ws + 256);
    _Float16* hmid  = (_Float16*)((char*)d_ws + 256 + 50331648);
    float*    hlast = (float*)((char*)d_ws + 256 + 50331648 + 33554432);

    hipMemsetAsync(d_ws, 0, 256, stream);

    const dim3 gemmGrid(512, 6);
    gemm_gx<<<gemmGrid, 256, 0, stream>>>(x, w_ih0, b_ih, gxbuf);

    // 10 blocks: 5 layers x 2 group-pairs; each block = 2 teams (1024 thr)
    gru_pipeline<<<NLAY * 2, 1024, 0, stream>>>(gxbuf, w_ih_rest, w_hh, b_ih, b_hh,
                                                hmid, hlast, flags);

    fc_kernel<<<BATCH, 128, 0, stream>>>(hlast, fc_w, fc_b, out);
}

// Round 10
// 886.322 us; speedup vs baseline: 7.8945x; 7.8945x over previous
//
#include <hip/hip_runtime.h>
#include <hip/hip_bf16.h>

// Problem constants
#define BATCH   64
#define SEQ     512
#define IN0     512
#define HID     128
#define G3      384   // 3*HID
#define NLAY    5
#define CHUNK   8     // handoff granularity (one release/acquire per CHUNK steps)

typedef _Float16 f16x8 __attribute__((ext_vector_type(8)));
typedef float    f32x4 __attribute__((ext_vector_type(4)));

static __device__ __forceinline__ float sigf(float x) {
    return __builtin_amdgcn_rcpf(1.f + __expf(-x));
}
static __device__ __forceinline__ float tanh_fast(float x) {
    // exp(-2|x|) = exp2(|x| * -2*log2(e)); single mul + v_exp
    const float e = exp2f(fabsf(x) * -2.885390082f);
    return copysignf((1.f - e) * __builtin_amdgcn_rcpf(1.f + e), x);
}

// ---------------------------------------------------------------------------
// gemm_gx (MFMA): gx0[32768][384] = x[32768][512] @ w_ih0[384][512]^T + b_ih0
// (unchanged)
// ---------------------------------------------------------------------------
__global__ __launch_bounds__(256) void gemm_gx(const float* __restrict__ A,
                                               const float* __restrict__ W,
                                               const float* __restrict__ bias,
                                               float* __restrict__ gx)
{
    __shared__ __align__(16) _Float16 As[64][40];   // [m][k0..31], pad 40 (80B rows)
    __shared__ __align__(16) _Float16 Bs[64][40];   // [n][k0..31]

    const int tid  = threadIdx.x;
    const int lane = tid & 63;
    const int wv   = tid >> 6;          // m-subtile
    const int n16  = lane & 15;
    const int quad = lane >> 4;
    const int row0 = blockIdx.x * 64;
    const int col0 = blockIdx.y * 64;
    const int r    = tid >> 2;          // staging row 0..63
    const int kc   = (tid & 3) * 8;     // staging k offset 0,8,16,24

    f32x4 acc[4];
    #pragma unroll
    for (int nt = 0; nt < 4; nt++) acc[nt] = (f32x4){0.f, 0.f, 0.f, 0.f};

    for (int k0 = 0; k0 < IN0; k0 += 32) {
        // ---- stage A (x) tile, f32 -> f16 ----
        {
            const float* Ap = A + (size_t)(row0 + r) * IN0 + k0 + kc;
            float4 a0 = *(const float4*)(Ap);
            float4 a1 = *(const float4*)(Ap + 4);
            f16x8 v;
            v[0] = (_Float16)a0.x; v[1] = (_Float16)a0.y; v[2] = (_Float16)a0.z; v[3] = (_Float16)a0.w;
            v[4] = (_Float16)a1.x; v[5] = (_Float16)a1.y; v[6] = (_Float16)a1.z; v[7] = (_Float16)a1.w;
            *(f16x8*)&As[r][kc] = v;
        }
        // ---- stage B (w_ih0) tile ----
        {
            const float* Wp = W + (size_t)(col0 + r) * IN0 + k0 + kc;
            float4 b0 = *(const float4*)(Wp);
            float4 b1 = *(const float4*)(Wp + 4);
            f16x8 v;
            v[0] = (_Float16)b0.x; v[1] = (_Float16)b0.y; v[2] = (_Float16)b0.z; v[3] = (_Float16)b0.w;
            v[4] = (_Float16)b1.x; v[5] = (_Float16)b1.y; v[6] = (_Float16)b1.z; v[7] = (_Float16)b1.w;
            *(f16x8*)&Bs[r][kc] = v;
        }
        __syncthreads();

        const f16x8 af = *(const f16x8*)&As[wv * 16 + n16][quad * 8];
        #pragma unroll
        for (int nt = 0; nt < 4; nt++) {
            const f16x8 bfr = *(const f16x8*)&Bs[nt * 16 + n16][quad * 8];
            acc[nt] = __builtin_amdgcn_mfma_f32_16x16x32_f16(af, bfr, acc[nt], 0, 0, 0);
        }
        __syncthreads();
    }

    // epilogue: bias + store (lane owns rows quad*4+r4 of subtile, col n16)
    #pragma unroll
    for (int nt = 0; nt < 4; nt++) {
        const int col = col0 + nt * 16 + n16;
        const float bb = bias[col];
        #pragma unroll
        for (int r4 = 0; r4 < 4; r4++) {
            const int row = row0 + wv * 16 + quad * 4 + r4;
            gx[(size_t)row * G3 + col] = acc[nt][r4] + bb;
        }
    }
}

// ---------------------------------------------------------------------------
// gru_pipeline (R20): R15 structure restored VERBATIM (proven 751 us;
// 1024-thread team variants are dead — gfx950 backend caps 1024-thr blocks
// at 64 VGPR regardless of launch_bounds / waves_per_eu attributes), plus
// two independent micro-cuts:
//   (a) per-step barrier poll is a PURE SPIN (no s_sleep): drops the 64-cy
//       wake quantum from the barrier-exit critical path.
//   (b) l==4 skips the chunk-end __syncthreads pair (no flush/release on
//       the last layer; ring-slot reuse is protected by the 8 intervening
//       per-step barriers). Last layer's chunk boundary is pure critical
//       path (~16 us total).
// ---------------------------------------------------------------------------
__global__ __launch_bounds__(512, 2) void gru_pipeline(
    const float* __restrict__ gx0,        // [64][512][384]
    const float* __restrict__ w_ih_rest,  // [4][384][128]
    const float* __restrict__ w_hh,       // [5][384][128]
    const float* __restrict__ b_ih,       // [5][384]
    const float* __restrict__ b_hh,       // [5][384]
    _Float16* __restrict__ hmid,          // [4][4][512][16][128]
    float* __restrict__ hlast,            // [64][128]
    int* __restrict__ flags)              // [16]
{
    const int l    = blockIdx.x >> 2;
    const int g    = blockIdx.x & 3;
    const int bm0  = g * 16;
    const int tid  = threadIdx.x;
    const int lane = tid & 63;
    const int n16  = lane & 15;
    const int quad = lane >> 4;
    const int wv   = tid >> 6;
    const int j    = wv * 16 + n16;       // hidden index this lane finalizes

    __shared__ __align__(16) _Float16 hS[CHUNK][16][136];   // h ring: h(t) at hS[t&7]
    __shared__ int barcnt;

    // ---- B-frags for w_hh ----
    f16x8 bf[3][4];
    {
        const float* wb = w_hh + (size_t)l * G3 * HID;
        #pragma unroll
        for (int tau = 0; tau < 3; tau++)
            #pragma unroll
            for (int kc = 0; kc < 4; kc++) {
                const float* wp = wb + (size_t)(tau * 128 + j) * HID + kc * 32 + quad * 8;
                f16x8 v;
                #pragma unroll
                for (int i = 0; i < 8; i++) v[i] = (_Float16)wp[i];
                bf[tau][kc] = v;
            }
    }
    // ---- B-frags for w_ih (layers >= 1) ----
    f16x8 bi[3][4];
    if (l > 0) {
        const float* wb = w_ih_rest + (size_t)(l - 1) * G3 * HID;
        #pragma unroll
        for (int tau = 0; tau < 3; tau++)
            #pragma unroll
            for (int kc = 0; kc < 4; kc++) {
                const float* wp = wb + (size_t)(tau * 128 + j) * HID + kc * 32 + quad * 8;
                f16x8 v;
                #pragma unroll
                for (int i = 0; i < 8; i++) v[i] = (_Float16)wp[i];
                bi[tau][kc] = v;
            }
    }
    // gate biases (gx0 already contains b_ih for layer 0); folded into acc init
    const float bcr = b_hh[l * G3 + j]       + ((l > 0) ? b_ih[l * G3 + j]       : 0.f);
    const float bcz = b_hh[l * G3 + j + 128] + ((l > 0) ? b_ih[l * G3 + j + 128] : 0.f);
    const float bcn = b_hh[l * G3 + j + 256];                      // n-gate: b_hh inside r*(...)
    const float bxn = (l > 0) ? b_ih[l * G3 + j + 256] : 0.f;      // n-gate: b_ih outside

    // ---- zero h ring (hS[7] is h(-1) = 0 for the first step) ----
    for (int i = tid; i < CHUNK * 16 * 136; i += 512) ((_Float16*)hS)[i] = (_Float16)0.f;
    float vhp[4] = {0.f, 0.f, 0.f, 0.f};
    if (tid == 0) barcnt = 0;

    // ---- layer-0 gx pointers + preload t=0 ----
    const float* pR[4];
    float xr[4], xz[4], xn[4];
    if (l == 0) {
        #pragma unroll
        for (int r = 0; r < 4; r++) {
            pR[r] = gx0 + (size_t)(bm0 + quad * 4 + r) * SEQ * G3 + j;
            xr[r] = pR[r][0]; xz[r] = pR[r][128]; xn[r] = pR[r][256];
            pR[r] += G3;
        }
    }

    const _Float16* hprev = (l > 0) ? hmid + (size_t)((l - 1) * 4 + g) * SEQ * 2048 : (const _Float16*)nullptr;
    _Float16*       hpub  = (l < 4) ? hmid + (size_t)(l * 4 + g) * SEQ * 2048 : (_Float16*)nullptr;
    int*       dstflag = (l < 4) ? &flags[l * 4 + g] : (int*)nullptr;
    const int* srcflag = (l > 0) ? &flags[(l - 1) * 4 + g] : (const int*)nullptr;

    f16x8 ap[4];                             // h_prev(t) A-frags
    const int hoff = n16 * 128 + quad * 8;   // A-frag base (m=n16, k=quad*8)

    __syncthreads();   // hS zero + barcnt visible

    volatile int* bc = &barcnt;
    int btarget = 0;

    for (int c = 0; c < SEQ / CHUNK; c++) {
        const int t0 = c * CHUNK;

        if (l > 0) {
            // once-per-chunk: relaxed spin, then ONE acquire load (buffer_inv)
            const int need = t0 + CHUNK;
            int v = __hip_atomic_load(srcflag, __ATOMIC_RELAXED, __HIP_MEMORY_SCOPE_AGENT);
            while (v < need) {
                __builtin_amdgcn_s_sleep(2);
                v = __hip_atomic_load(srcflag, __ATOMIC_RELAXED, __HIP_MEMORY_SCOPE_AGENT);
            }
            (void)__hip_atomic_load(srcflag, __ATOMIC_ACQUIRE, __HIP_MEMORY_SCOPE_AGENT);
            __asm__ volatile("" ::: "memory");
            const _Float16* hp = hprev + (size_t)t0 * 2048 + hoff;
            #pragma unroll
            for (int kc = 0; kc < 4; kc++) ap[kc] = *(const f16x8*)(hp + kc * 32);
        }

        #pragma unroll
        for (int i = 0; i < CHUNK; i++) {
            const int t = t0 + i;

            // ---- LDS flag barrier: no vmcnt drain; PURE SPIN (no s_sleep) ----
            __asm__ volatile("" ::: "memory");
            if (lane == 0) atomicAdd(&barcnt, 1);
            btarget += 8;
            while (*bc < btarget) { /* pure spin: volatile LDS read */ }
            __asm__ volatile("" ::: "memory");

            // issue af LDS reads first (latency overlapped by ih MFMAs below)
            const int rb = (i + CHUNK - 1) & (CHUNK - 1);   // h(t-1) slot (compile-time per i)
            f16x8 af[4];
            #pragma unroll
            for (int kc = 0; kc < 4; kc++)
                af[kc] = *(const f16x8*)&hS[rb][n16][kc * 32 + quad * 8];

            // ih MFMAs (register inputs, no LDS dependency) — issue first.
            // bias folding: ai2 starts at bxn (n-gate b_ih, outside r*()).
            f32x4 ai0 = {0.f, 0.f, 0.f, 0.f}, ai1 = ai0;
            f32x4 ai2 = {bxn, bxn, bxn, bxn};
            if (l > 0) {
                #pragma unroll
                for (int kc = 0; kc < 4; kc++) {
                    ai0 = __builtin_amdgcn_mfma_f32_16x16x32_f16(ap[kc], bi[0][kc], ai0, 0, 0, 0);
                    ai1 = __builtin_amdgcn_mfma_f32_16x16x32_f16(ap[kc], bi[1][kc], ai1, 0, 0, 0);
                    ai2 = __builtin_amdgcn_mfma_f32_16x16x32_f16(ap[kc], bi[2][kc], ai2, 0, 0, 0);
                }
            }

            // EARLY in-chunk prefetch of h_prev(t+1): ap is dead after the ih
            // MFMAs above; hh MFMAs + finalize + barrier cover the latency.
            if (l > 0 && i < CHUNK - 1) {
                const _Float16* hp = hprev + (size_t)(t + 1) * 2048 + hoff;
                #pragma unroll
                for (int kc = 0; kc < 4; kc++) ap[kc] = *(const f16x8*)(hp + kc * 32);
            }

            // layer-0: issue gx(t+1) prefetch
            float nr[4], nz[4], nn[4];
            if (l == 0) {
                #pragma unroll
                for (int r = 0; r < 4; r++) {
                    nr[r] = pR[r][0]; nz[r] = pR[r][128]; nn[r] = pR[r][256];
                }
                if (t + 1 < SEQ) {
                    #pragma unroll
                    for (int r = 0; r < 4; r++) pR[r] += G3;
                }
            }

            // hh MFMAs — biases folded into C-init (bcr, bcz, bcn)
            f32x4 ah0 = {bcr, bcr, bcr, bcr};
            f32x4 ah1 = {bcz, bcz, bcz, bcz};
            f32x4 ah2 = {bcn, bcn, bcn, bcn};
            #pragma unroll
            for (int kc = 0; kc < 4; kc++) {
                ah0 = __builtin_amdgcn_mfma_f32_16x16x32_f16(af[kc], bf[0][kc], ah0, 0, 0, 0);
                ah1 = __builtin_amdgcn_mfma_f32_16x16x32_f16(af[kc], bf[1][kc], ah1, 0, 0, 0);
                ah2 = __builtin_amdgcn_mfma_f32_16x16x32_f16(af[kc], bf[2][kc], ah2, 0, 0, 0);
            }

            // finalize: lane owns (m = quad*4+r, j) for all gates
            #pragma unroll
            for (int r = 0; r < 4; r++) {
                const float sxr = (l == 0) ? xr[r] : ai0[r];
                const float sxz = (l == 0) ? xz[r] : ai1[r];
                const float sxn = (l == 0) ? xn[r] : ai2[r];
                const float rg  = sigf(sxr + ah0[r]);
                const float zg  = sigf(sxz + ah1[r]);
                const float th  = tanh_fast(fmaf(rg, ah2[r], sxn));
                const float hnew = fmaf(zg, vhp[r] - th, th);   // (1-z)n + z h
                vhp[r] = hnew;
                hS[i][quad * 4 + r][j] = (_Float16)hnew;        // single h write (ring)
                if (l == 4 && t == SEQ - 1)
                    hlast[(bm0 + quad * 4 + r) * 128 + j] = hnew;
            }

            if (l == 0) {
                #pragma unroll
                for (int r = 0; r < 4; r++) { xr[r] = nr[r]; xz[r] = nz[r]; xn[r] = nn[r]; }
            }
        }

        // ---- chunk boundary (producers only): flush ring -> hmid, RELEASE.
        // l==4 skips entirely: no flush/release; the per-step flag barrier
        // alone protects hS ring reuse (slot rewritten 8 barriers after its
        // last read).
        if (l < 4) {
            __syncthreads();                   // all waves' hS writes visible
            _Float16* dstc = hpub + (size_t)t0 * 2048;
            {
                const int seg0 = tid;            // 0..511
                const int seg1 = tid + 512;
                const int seg2 = tid + 1024;
                const int seg3 = tid + 1536;
                f16x8 v0 = *(const f16x8*)&hS[(seg0 >> 8)][(seg0 >> 4) & 15][(seg0 & 15) * 8];
                f16x8 v1 = *(const f16x8*)&hS[(seg1 >> 8)][(seg1 >> 4) & 15][(seg1 & 15) * 8];
                f16x8 v2 = *(const f16x8*)&hS[(seg2 >> 8)][(seg2 >> 4) & 15][(seg2 & 15) * 8];
                f16x8 v3 = *(const f16x8*)&hS[(seg3 >> 8)][(seg3 >> 4) & 15][(seg3 & 15) * 8];
                *(f16x8*)(dstc + (seg0 >> 4) * 128 + (seg0 & 15) * 8) = v0;
                *(f16x8*)(dstc + (seg1 >> 4) * 128 + (seg1 & 15) * 8) = v1;
                *(f16x8*)(dstc + (seg2 >> 4) * 128 + (seg2 & 15) * 8) = v2;
                *(f16x8*)(dstc + (seg3 >> 4) * 128 + (seg3 & 15) * 8) = v3;
            }
            __syncthreads();                   // drains vmcnt (stores retired)
            if (tid == 0)
                __hip_atomic_store(dstflag, t0 + CHUNK, __ATOMIC_RELEASE, __HIP_MEMORY_SCOPE_AGENT);
        }
    }
}

// ---------------------------------------------------------------------------
// fc: out[b][o] = hlast[b][:] . fc_w[o][:] + fc_b[o]
// ---------------------------------------------------------------------------
__global__ __launch_bounds__(128) void fc_kernel(const float* __restrict__ hlast,
                                                 const float* __restrict__ fc_w,
                                                 const float* __restrict__ fc_b,
                                                 float* __restrict__ out)
{
    const int b = blockIdx.x;
    const int o = threadIdx.x;
    if (o < 96) {
        const float* h = hlast + (size_t)b * HID;
        const float* wrow = fc_w + o * HID;
        float acc = fc_b[o];
        #pragma unroll 4
        for (int k = 0; k < HID; k++) acc = fmaf(h[k], wrow[k], acc);
        out[b * 96 + o] = acc;
    }
}

// ---------------------------------------------------------------------------
extern "C" void kernel_launch(void* const* d_in, const int* in_sizes, int n_in,
                              void* d_out, int out_size, void* d_ws, size_t ws_size,
                              hipStream_t stream)
{
    const float* x         = (const float*)d_in[0]; // [64][512][512]
    const float* w_ih0     = (const float*)d_in[1]; // [384][512]
    const float* w_ih_rest = (const float*)d_in[2]; // [4][384][128]
    const float* w_hh      = (const float*)d_in[3]; // [5][384][128]
    const float* b_ih      = (const float*)d_in[4]; // [5][384]
    const float* b_hh      = (const float*)d_in[5]; // [5][384]
    const float* fc_w      = (const float*)d_in[6]; // [96][128]
    const float* fc_b      = (const float*)d_in[7]; // [96]
    float* out = (float*)d_out;                     // [64][96]

    // workspace layout:
    //   [0,256)              flags (16 ints, zeroed each launch)
    //   [256, +50331648)     gxbuf fp32 [64][512][384]
    //   [.., +33554432)      hmid  f16  [4][4][512][16][128]
    //   [.., +32768)         hlast fp32 [64][128]
    int*      flags = (int*)d_ws;
    float*    gxbuf = (float*)((char*)d_ws + 256);
    _Float16* hmid  = (_Float16*)((char*)d_ws + 256 + 50331648);
    float*    hlast = (float*)((char*)d_ws + 256 + 50331648 + 33554432);

    hipMemsetAsync(d_ws, 0, 256, stream);

    const dim3 gemmGrid(512, 6);
    gemm_gx<<<gemmGrid, 256, 0, stream>>>(x, w_ih0, b_ih, gxbuf);

    gru_pipeline<<<NLAY * 4, 512, 0, stream>>>(gxbuf, w_ih_rest, w_hh, b_ih, b_hh,
                                               hmid, hlast, flags);

    fc_kernel<<<BATCH, 128, 0, stream>>>(hlast, fc_w, fc_b, out);
}

// Round 12
// 863.474 us; speedup vs baseline: 8.1033x; 1.0265x over previous
//
#include <hip/hip_runtime.h>
#include <hip/hip_bf16.h>

// Problem constants
#define BATCH   64
#define SEQ     512
#define IN0     512
#define HID     128
#define G3      384   // 3*HID
#define NLAY    5
#define CHUNK   8     // handoff granularity (one release/acquire per CHUNK steps)

typedef _Float16 f16x8 __attribute__((ext_vector_type(8)));
typedef float    f32x4 __attribute__((ext_vector_type(4)));

static __device__ __forceinline__ float sigf(float x) {
    return __builtin_amdgcn_rcpf(1.f + __expf(-x));
}
static __device__ __forceinline__ float tanh_fast(float x) {
    // exp(-2|x|) = exp2(|x| * -2*log2(e)); single mul + v_exp
    const float e = exp2f(fabsf(x) * -2.885390082f);
    return copysignf((1.f - e) * __builtin_amdgcn_rcpf(1.f + e), x);
}

// ---------------------------------------------------------------------------
// gemm_gx (MFMA): gx0[32768][384] = x[32768][512] @ w_ih0[384][512]^T + b_ih0
// (unchanged)
// ---------------------------------------------------------------------------
__global__ __launch_bounds__(256) void gemm_gx(const float* __restrict__ A,
                                               const float* __restrict__ W,
                                               const float* __restrict__ bias,
                                               float* __restrict__ gx)
{
    __shared__ __align__(16) _Float16 As[64][40];   // [m][k0..31], pad 40 (80B rows)
    __shared__ __align__(16) _Float16 Bs[64][40];   // [n][k0..31]

    const int tid  = threadIdx.x;
    const int lane = tid & 63;
    const int wv   = tid >> 6;          // m-subtile
    const int n16  = lane & 15;
    const int quad = lane >> 4;
    const int row0 = blockIdx.x * 64;
    const int col0 = blockIdx.y * 64;
    const int r    = tid >> 2;          // staging row 0..63
    const int kc   = (tid & 3) * 8;     // staging k offset 0,8,16,24

    f32x4 acc[4];
    #pragma unroll
    for (int nt = 0; nt < 4; nt++) acc[nt] = (f32x4){0.f, 0.f, 0.f, 0.f};

    for (int k0 = 0; k0 < IN0; k0 += 32) {
        // ---- stage A (x) tile, f32 -> f16 ----
        {
            const float* Ap = A + (size_t)(row0 + r) * IN0 + k0 + kc;
            float4 a0 = *(const float4*)(Ap);
            float4 a1 = *(const float4*)(Ap + 4);
            f16x8 v;
            v[0] = (_Float16)a0.x; v[1] = (_Float16)a0.y; v[2] = (_Float16)a0.z; v[3] = (_Float16)a0.w;
            v[4] = (_Float16)a1.x; v[5] = (_Float16)a1.y; v[6] = (_Float16)a1.z; v[7] = (_Float16)a1.w;
            *(f16x8*)&As[r][kc] = v;
        }
        // ---- stage B (w_ih0) tile ----
        {
            const float* Wp = W + (size_t)(col0 + r) * IN0 + k0 + kc;
            float4 b0 = *(const float4*)(Wp);
            float4 b1 = *(const float4*)(Wp + 4);
            f16x8 v;
            v[0] = (_Float16)b0.x; v[1] = (_Float16)b0.y; v[2] = (_Float16)b0.z; v[3] = (_Float16)b0.w;
            v[4] = (_Float16)b1.x; v[5] = (_Float16)b1.y; v[6] = (_Float16)b1.z; v[7] = (_Float16)b1.w;
            *(f16x8*)&Bs[r][kc] = v;
        }
        __syncthreads();

        const f16x8 af = *(const f16x8*)&As[wv * 16 + n16][quad * 8];
        #pragma unroll
        for (int nt = 0; nt < 4; nt++) {
            const f16x8 bfr = *(const f16x8*)&Bs[nt * 16 + n16][quad * 8];
            acc[nt] = __builtin_amdgcn_mfma_f32_16x16x32_f16(af, bfr, acc[nt], 0, 0, 0);
        }
        __syncthreads();
    }

    // epilogue: bias + store (lane owns rows quad*4+r4 of subtile, col n16)
    #pragma unroll
    for (int nt = 0; nt < 4; nt++) {
        const int col = col0 + nt * 16 + n16;
        const float bb = bias[col];
        #pragma unroll
        for (int r4 = 0; r4 < 4; r4++) {
            const int row = row0 + wv * 16 + quad * 4 + r4;
            gx[(size_t)row * G3 + col] = acc[nt][r4] + bb;
        }
    }
}

// ---------------------------------------------------------------------------
// gru_pipeline (R21 resubmit): R20 base (proven 740 us) with ONE change —
// the per-step barrier's arrival is de-serialized:
//   OLD: 8 waves atomicAdd the SAME LDS address (LDS RMWs to one address
//        serialize in the DS pipe: ~8x30 cy of arrival serialization/step).
//   NEW: distributed slots bslots[8]; arrive = lane0 plain ds_write of the
//        step counter to bslots[wv] (parallel, 8 banks, no RMW; same
//        in-order-DS-queue guarantee orders it behind the wave's hS writes);
//        wait = all lanes poll bslots[lane&7] (broadcast, conflict-free)
//        until __all(v >= step).
// ---------------------------------------------------------------------------
__global__ __launch_bounds__(512, 2) void gru_pipeline(
    const float* __restrict__ gx0,        // [64][512][384]
    const float* __restrict__ w_ih_rest,  // [4][384][128]
    const float* __restrict__ w_hh,       // [5][384][128]
    const float* __restrict__ b_ih,       // [5][384]
    const float* __restrict__ b_hh,       // [5][384]
    _Float16* __restrict__ hmid,          // [4][4][512][16][128]
    float* __restrict__ hlast,            // [64][128]
    int* __restrict__ flags)              // [16]
{
    const int l    = blockIdx.x >> 2;
    const int g    = blockIdx.x & 3;
    const int bm0  = g * 16;
    const int tid  = threadIdx.x;
    const int lane = tid & 63;
    const int n16  = lane & 15;
    const int quad = lane >> 4;
    const int wv   = tid >> 6;
    const int j    = wv * 16 + n16;       // hidden index this lane finalizes

    __shared__ __align__(16) _Float16 hS[CHUNK][16][136];   // h ring: h(t) at hS[t&7]
    __shared__ __align__(16) int bslots[8];                 // per-wave arrival slots

    // ---- B-frags for w_hh ----
    f16x8 bf[3][4];
    {
        const float* wb = w_hh + (size_t)l * G3 * HID;
        #pragma unroll
        for (int tau = 0; tau < 3; tau++)
            #pragma unroll
            for (int kc = 0; kc < 4; kc++) {
                const float* wp = wb + (size_t)(tau * 128 + j) * HID + kc * 32 + quad * 8;
                f16x8 v;
                #pragma unroll
                for (int i = 0; i < 8; i++) v[i] = (_Float16)wp[i];
                bf[tau][kc] = v;
            }
    }
    // ---- B-frags for w_ih (layers >= 1) ----
    f16x8 bi[3][4];
    if (l > 0) {
        const float* wb = w_ih_rest + (size_t)(l - 1) * G3 * HID;
        #pragma unroll
        for (int tau = 0; tau < 3; tau++)
            #pragma unroll
            for (int kc = 0; kc < 4; kc++) {
                const float* wp = wb + (size_t)(tau * 128 + j) * HID + kc * 32 + quad * 8;
                f16x8 v;
                #pragma unroll
                for (int i = 0; i < 8; i++) v[i] = (_Float16)wp[i];
                bi[tau][kc] = v;
            }
    }
    // gate biases (gx0 already contains b_ih for layer 0); folded into acc init
    const float bcr = b_hh[l * G3 + j]       + ((l > 0) ? b_ih[l * G3 + j]       : 0.f);
    const float bcz = b_hh[l * G3 + j + 128] + ((l > 0) ? b_ih[l * G3 + j + 128] : 0.f);
    const float bcn = b_hh[l * G3 + j + 256];                      // n-gate: b_hh inside r*(...)
    const float bxn = (l > 0) ? b_ih[l * G3 + j + 256] : 0.f;      // n-gate: b_ih outside

    // ---- zero h ring (hS[7] is h(-1) = 0 for the first step) ----
    for (int i = tid; i < CHUNK * 16 * 136; i += 512) ((_Float16*)hS)[i] = (_Float16)0.f;
    float vhp[4] = {0.f, 0.f, 0.f, 0.f};
    if (tid < 8) bslots[tid] = 0;

    // ---- layer-0 gx pointers + preload t=0 ----
    const float* pR[4];
    float xr[4], xz[4], xn[4];
    if (l == 0) {
        #pragma unroll
        for (int r = 0; r < 4; r++) {
            pR[r] = gx0 + (size_t)(bm0 + quad * 4 + r) * SEQ * G3 + j;
            xr[r] = pR[r][0]; xz[r] = pR[r][128]; xn[r] = pR[r][256];
            pR[r] += G3;
        }
    }

    const _Float16* hprev = (l > 0) ? hmid + (size_t)((l - 1) * 4 + g) * SEQ * 2048 : (const _Float16*)nullptr;
    _Float16*       hpub  = (l < 4) ? hmid + (size_t)(l * 4 + g) * SEQ * 2048 : (_Float16*)nullptr;
    int*       dstflag = (l < 4) ? &flags[l * 4 + g] : (int*)nullptr;
    const int* srcflag = (l > 0) ? &flags[(l - 1) * 4 + g] : (const int*)nullptr;

    f16x8 ap[4];                             // h_prev(t) A-frags
    const int hoff = n16 * 128 + quad * 8;   // A-frag base (m=n16, k=quad*8)

    __syncthreads();   // hS zero + bslots visible

    volatile int* vb = bslots;
    const int myslot = lane & 7;

    for (int c = 0; c < SEQ / CHUNK; c++) {
        const int t0 = c * CHUNK;

        if (l > 0) {
            // once-per-chunk: relaxed spin, then ONE acquire load (buffer_inv)
            const int need = t0 + CHUNK;
            int v = __hip_atomic_load(srcflag, __ATOMIC_RELAXED, __HIP_MEMORY_SCOPE_AGENT);
            while (v < need) {
                __builtin_amdgcn_s_sleep(2);
                v = __hip_atomic_load(srcflag, __ATOMIC_RELAXED, __HIP_MEMORY_SCOPE_AGENT);
            }
            (void)__hip_atomic_load(srcflag, __ATOMIC_ACQUIRE, __HIP_MEMORY_SCOPE_AGENT);
            __asm__ volatile("" ::: "memory");
            const _Float16* hp = hprev + (size_t)t0 * 2048 + hoff;
            #pragma unroll
            for (int kc = 0; kc < 4; kc++) ap[kc] = *(const f16x8*)(hp + kc * 32);
        }

        #pragma unroll
        for (int i = 0; i < CHUNK; i++) {
            const int t = t0 + i;
            const int sc = t + 1;   // step counter for this barrier

            // ---- distributed-slot flag barrier: no vmcnt drain ----
            // arrive: plain ds_write (DS-pipe ordered after this wave's prev
            // hS writes); parallel across waves (8 banks, no RMW serialization)
            __asm__ volatile("" ::: "memory");
            if (lane == 0) vb[wv] = sc;
            // wait: 8-slot broadcast poll until all waves arrived
            {
                int v;
                do { v = vb[myslot]; } while (!__all(v >= sc));
            }
            __asm__ volatile("" ::: "memory");

            // issue af LDS reads first (latency overlapped by ih MFMAs below)
            const int rb = (i + CHUNK - 1) & (CHUNK - 1);   // h(t-1) slot (compile-time per i)
            f16x8 af[4];
            #pragma unroll
            for (int kc = 0; kc < 4; kc++)
                af[kc] = *(const f16x8*)&hS[rb][n16][kc * 32 + quad * 8];

            // ih MFMAs (register inputs, no LDS dependency) — issue first.
            // bias folding: ai2 starts at bxn (n-gate b_ih, outside r*()).
            f32x4 ai0 = {0.f, 0.f, 0.f, 0.f}, ai1 = ai0;
            f32x4 ai2 = {bxn, bxn, bxn, bxn};
            if (l > 0) {
                #pragma unroll
                for (int kc = 0; kc < 4; kc++) {
                    ai0 = __builtin_amdgcn_mfma_f32_16x16x32_f16(ap[kc], bi[0][kc], ai0, 0, 0, 0);
                    ai1 = __builtin_amdgcn_mfma_f32_16x16x32_f16(ap[kc], bi[1][kc], ai1, 0, 0, 0);
                    ai2 = __builtin_amdgcn_mfma_f32_16x16x32_f16(ap[kc], bi[2][kc], ai2, 0, 0, 0);
                }
            }

            // EARLY in-chunk prefetch of h_prev(t+1): ap is dead after the ih
            // MFMAs above; hh MFMAs + finalize + barrier cover the latency.
            if (l > 0 && i < CHUNK - 1) {
                const _Float16* hp = hprev + (size_t)(t + 1) * 2048 + hoff;
                #pragma unroll
                for (int kc = 0; kc < 4; kc++) ap[kc] = *(const f16x8*)(hp + kc * 32);
            }

            // layer-0: issue gx(t+1) prefetch
            float nr[4], nz[4], nn[4];
            if (l == 0) {
                #pragma unroll
                for (int r = 0; r < 4; r++) {
                    nr[r] = pR[r][0]; nz[r] = pR[r][128]; nn[r] = pR[r][256];
                }
                if (t + 1 < SEQ) {
                    #pragma unroll
                    for (int r = 0; r < 4; r++) pR[r] += G3;
                }
            }

            // hh MFMAs — biases folded into C-init (bcr, bcz, bcn)
            f32x4 ah0 = {bcr, bcr, bcr, bcr};
            f32x4 ah1 = {bcz, bcz, bcz, bcz};
            f32x4 ah2 = {bcn, bcn, bcn, bcn};
            #pragma unroll
            for (int kc = 0; kc < 4; kc++) {
                ah0 = __builtin_amdgcn_mfma_f32_16x16x32_f16(af[kc], bf[0][kc], ah0, 0, 0, 0);
                ah1 = __builtin_amdgcn_mfma_f32_16x16x32_f16(af[kc], bf[1][kc], ah1, 0, 0, 0);
                ah2 = __builtin_amdgcn_mfma_f32_16x16x32_f16(af[kc], bf[2][kc], ah2, 0, 0, 0);
            }

            // finalize: lane owns (m = quad*4+r, j) for all gates
            #pragma unroll
            for (int r = 0; r < 4; r++) {
                const float sxr = (l == 0) ? xr[r] : ai0[r];
                const float sxz = (l == 0) ? xz[r] : ai1[r];
                const float sxn = (l == 0) ? xn[r] : ai2[r];
                const float rg  = sigf(sxr + ah0[r]);
                const float zg  = sigf(sxz + ah1[r]);
                const float th  = tanh_fast(fmaf(rg, ah2[r], sxn));
                const float hnew = fmaf(zg, vhp[r] - th, th);   // (1-z)n + z h
                vhp[r] = hnew;
                hS[i][quad * 4 + r][j] = (_Float16)hnew;        // single h write (ring)
                if (l == 4 && t == SEQ - 1)
                    hlast[(bm0 + quad * 4 + r) * 128 + j] = hnew;
            }

            if (l == 0) {
                #pragma unroll
                for (int r = 0; r < 4; r++) { xr[r] = nr[r]; xz[r] = nz[r]; xn[r] = nn[r]; }
            }
        }

        // ---- chunk boundary (producers only): flush ring -> hmid, RELEASE.
        // l==4 skips entirely: no flush/release; the per-step flag barrier
        // alone protects hS ring reuse (slot rewritten 8 barriers after its
        // last read).
        if (l < 4) {
            __syncthreads();                   // all waves' hS writes visible
            _Float16* dstc = hpub + (size_t)t0 * 2048;
            {
                const int seg0 = tid;            // 0..511
                const int seg1 = tid + 512;
                const int seg2 = tid + 1024;
                const int seg3 = tid + 1536;
                f16x8 v0 = *(const f16x8*)&hS[(seg0 >> 8)][(seg0 >> 4) & 15][(seg0 & 15) * 8];
                f16x8 v1 = *(const f16x8*)&hS[(seg1 >> 8)][(seg1 >> 4) & 15][(seg1 & 15) * 8];
                f16x8 v2 = *(const f16x8*)&hS[(seg2 >> 8)][(seg2 >> 4) & 15][(seg2 & 15) * 8];
                f16x8 v3 = *(const f16x8*)&hS[(seg3 >> 8)][(seg3 >> 4) & 15][(seg3 & 15) * 8];
                *(f16x8*)(dstc + (seg0 >> 4) * 128 + (seg0 & 15) * 8) = v0;
                *(f16x8*)(dstc + (seg1 >> 4) * 128 + (seg1 & 15) * 8) = v1;
                *(f16x8*)(dstc + (seg2 >> 4) * 128 + (seg2 & 15) * 8) = v2;
                *(f16x8*)(dstc + (seg3 >> 4) * 128 + (seg3 & 15) * 8) = v3;
            }
            __syncthreads();                   // drains vmcnt (stores retired)
            if (tid == 0)
                __hip_atomic_store(dstflag, t0 + CHUNK, __ATOMIC_RELEASE, __HIP_MEMORY_SCOPE_AGENT);
        }
    }
}

// ---------------------------------------------------------------------------
// fc: out[b][o] = hlast[b][:] . fc_w[o][:] + fc_b[o]
// ---------------------------------------------------------------------------
__global__ __launch_bounds__(128) void fc_kernel(const float* __restrict__ hlast,
                                                 const float* __restrict__ fc_w,
                                                 const float* __restrict__ fc_b,
                                                 float* __restrict__ out)
{
    const int b = blockIdx.x;
    const int o = threadIdx.x;
    if (o < 96) {
        const float* h = hlast + (size_t)b * HID;
        const float* wrow = fc_w + o * HID;
        float acc = fc_b[o];
        #pragma unroll 4
        for (int k = 0; k < HID; k++) acc = fmaf(h[k], wrow[k], acc);
        out[b * 96 + o] = acc;
    }
}

// ---------------------------------------------------------------------------
extern "C" void kernel_launch(void* const* d_in, const int* in_sizes, int n_in,
                              void* d_out, int out_size, void* d_ws, size_t ws_size,
                              hipStream_t stream)
{
    const float* x         = (const float*)d_in[0]; // [64][512][512]
    const float* w_ih0     = (const float*)d_in[1]; // [384][512]
    const float* w_ih_rest = (const float*)d_in[2]; // [4][384][128]
    const float* w_hh      = (const float*)d_in[3]; // [5][384][128]
    const float* b_ih      = (const float*)d_in[4]; // [5][384]
    const float* b_hh      = (const float*)d_in[5]; // [5][384]
    const float* fc_w      = (const float*)d_in[6]; // [96][128]
    const float* fc_b      = (const float*)d_in[7]; // [96]
    float* out = (float*)d_out;                     // [64][96]

    // workspace layout:
    //   [0,256)              flags (16 ints, zeroed each launch)
    //   [256, +50331648)     gxbuf fp32 [64][512][384]
    //   [.., +33554432)      hmid  f16  [4][4][512][16][128]
    //   [.., +32768)         hlast fp32 [64][128]
    int*      flags = (int*)d_ws;
    float*    gxbuf = (float*)((char*)d_ws + 256);
    _Float16* hmid  = (_Float16*)((char*)d_ws + 256 + 50331648);
    float*    hlast = (float*)((char*)d_ws + 256 + 50331648 + 33554432);

    hipMemsetAsync(d_ws, 0, 256, stream);

    const dim3 gemmGrid(512, 6);
    gemm_gx<<<gemmGrid, 256, 0, stream>>>(x, w_ih0, b_ih, gxbuf);

    gru_pipeline<<<NLAY * 4, 512, 0, stream>>>(gxbuf, w_ih_rest, w_hh, b_ih, b_hh,
                                               hmid, hlast, flags);

    fc_kernel<<<BATCH, 128, 0, stream>>>(hlast, fc_w, fc_b, out);
}